// Round 16
// baseline (340.495 us; speedup 1.0000x reference)
//
#include <hip/hip_runtime.h>
#include <hip/hip_bf16.h>

typedef unsigned short u16;
typedef __attribute__((ext_vector_type(8))) __bf16 bf16x8;
typedef __attribute__((ext_vector_type(4))) float f32x4;
typedef __attribute__((ext_vector_type(8))) unsigned short ushort8;

#define GM 8192
#define GN 4096
#define GK 4096
#define NT (GK / 64)  // 64 K-tiles of BK=64

__device__ __forceinline__ u16 f2bf(float f) {
  unsigned u = __float_as_uint(f);
  u += 0x7fffu + ((u >> 16) & 1u);
  return (u16)(u >> 16);
}

// ---- kernel 1: fused pre-pass (R15, kept).
// blocks [0, GN):        Weff[o][:] = bf16(W[o][:] + 2 * (B@A)[o][:])
// blocks [GN, GN+2048):  xb = bf16(x), 16 elems/thread
__global__ void prep(const float* __restrict__ W,
                     const float* __restrict__ lA,
                     const float* __restrict__ lB,
                     u16* __restrict__ Weff,
                     const float* __restrict__ x,
                     u16* __restrict__ xb) {
  const int bid = blockIdx.x;
  if (bid < GN) {
    const int o = bid;
    float b[8];
#pragma unroll
    for (int r = 0; r < 8; ++r) b[r] = 2.0f * lB[o * 8 + r];
    const float* wrow = W + (size_t)o * GK;
    u16* orow = Weff + (size_t)o * GK;
    for (int d = threadIdx.x * 4; d < GK; d += blockDim.x * 4) {
      float4 w = *reinterpret_cast<const float4*>(wrow + d);
      float a0 = w.x, a1 = w.y, a2 = w.z, a3 = w.w;
#pragma unroll
      for (int r = 0; r < 8; ++r) {
        float4 a = *reinterpret_cast<const float4*>(lA + r * GK + d);
        a0 += b[r] * a.x; a1 += b[r] * a.y; a2 += b[r] * a.z; a3 += b[r] * a.w;
      }
      ushort4 p;
      p.x = f2bf(a0); p.y = f2bf(a1); p.z = f2bf(a2); p.w = f2bf(a3);
      *reinterpret_cast<ushort4*>(orow + d) = p;
    }
  } else {
    const size_t base = ((size_t)(bid - GN) * 256 + threadIdx.x) * 16;
#pragma unroll
    for (int h = 0; h < 2; ++h) {
      const size_t i = base + h * 8;
      float4 v0 = *reinterpret_cast<const float4*>(x + i);
      float4 v1 = *reinterpret_cast<const float4*>(x + i + 4);
      ushort8 o;
      o[0] = f2bf(v0.x); o[1] = f2bf(v0.y); o[2] = f2bf(v0.z); o[3] = f2bf(v0.w);
      o[4] = f2bf(v1.x); o[5] = f2bf(v1.y); o[6] = f2bf(v1.z); o[7] = f2bf(v1.w);
      *reinterpret_cast<ushort8*>(xb + i) = o;
    }
  }
}

// ---- kernel 2: 128x128-tile free-flow GEMM, C[m][n] = sum_k A[m][k]*B[n][k]
// R16: same free-flow schedule as R11 (measured-best family), but 128x128
// tiles with 64 KiB LDS -> TWO independent blocks per CU. Diagnosis: the
// 256x2 structure has 1 block/CU, so its per-tile vmcnt+BAR+read-hump
// stalls the whole CU (no co-resident block to fill the bubble); 6 schedule
// variants all plateaued at ~4330 cyc/tile. With 2 blocks/CU the stalls
// decorrelate (block A's barrier overlaps block B's MFMA stream); setprio
// arbitrates in favor of the MFMA-phase block (T5's positive regime).
// Cost: 1.33x per-FLOP LDS-read traffic (B-panel reuse halves) + more L2
// panel re-reads (L3-absorbed; HBM was at 24%).
// 4 waves (2x2), per-wave 64x64 output: acc 64 + frags 64 + addr ~25 VGPR
// -> no spill possible at the 256-reg/2-wave budget. 3-bit LDS swizzle
// (same algebra, verified: store row bits 1-3 = (wv&1)<<3|(l>>3), read row
// bits 1-3 = l&15). XCD swizzle (2048 blocks, %8==0).
__device__ __forceinline__ void gload16(const u16* g, u16* l) {
  __builtin_amdgcn_global_load_lds(
      (const __attribute__((address_space(1))) void*)g,
      (__attribute__((address_space(3))) void*)l, 16, 0, 0);
}

#define BAR()                                  \
  do {                                         \
    asm volatile("" ::: "memory");             \
    __builtin_amdgcn_s_barrier();              \
    asm volatile("" ::: "memory");             \
  } while (0)

__global__ __launch_bounds__(256, 2) void gemm128(const u16* __restrict__ Ab,
                                                  const u16* __restrict__ Bb,
                                                  float* __restrict__ C) {
  // [buf][0=A,1=B][row*64 + k], 2*2*8192*2B = 64 KiB -> 2 blocks/CU
  __shared__ u16 lds[2][2][128 * 64];

  const int tid = threadIdx.x;
  const int wv = tid >> 6;   // 0..3
  const int l = tid & 63;

  // XCD-aware swizzle: 2048 blocks, %8 == 0 -> simple bijective form
  const int nwg = gridDim.x;
  const int cpx = nwg >> 3;
  const int wg = ((int)blockIdx.x & 7) * cpx + ((int)blockIdx.x >> 3);
  const int tm = wg >> 5;    // GN/128 = 32 tiles in N
  const int tn = wg & 31;

  const int wr = wv >> 1;    // 0..1 (M split: 64 rows/wave)
  const int wc = wv & 1;     // 0..1 (N split: 64 cols/wave)

  // --- staging constants ---
  // per wave: 4 gloads per operand; gload j covers rows j*32 + wv*8 + (l>>3)
  const int srow = (wv << 3) + (l >> 3);
  const int srl = ((wv & 1) << 3) | (l >> 3);          // row bits 0..3
  const int skel = ((l & 7) << 3) ^ ((srl & 0xE) << 2);
  const u16* aG = Ab + (size_t)(tm * 128) * GK;
  const u16* bG = Bb + (size_t)(tn * 128) * GK;

  // --- reader constants ---
  const int frow = l & 15;
  const int fksw = ((l >> 4) << 3) ^ ((frow & 0xE) << 2);
  const int arow = wr * 64 + frow;
  const int brow = wc * 64 + frow;

  // stage one operand tile (A: r=0, B: r=1): 4 x gload16/wave
  auto STAGE = [&](int th, int r) {
    const int tc = th < NT ? th : NT - 1;  // clamp (tail garbage never read)
    const int k0 = tc << 6;
    const u16* src = (r == 0 ? aG : bG) + (size_t)srow * GK + k0 + skel;
    u16* dst = &lds[th & 1][r][wv * 512];
#pragma unroll
    for (int j = 0; j < 4; ++j)
      gload16(src + (size_t)(j * 32) * GK, dst + j * 2048);
  };

  // prologue: stage tile 0 only (1-deep pipeline)
  STAGE(0, 0); STAGE(0, 1);

  f32x4 acc[4][4] = {};          // 64 VGPR
  bf16x8 af[4][2], bf[4][2];     // 64 VGPR

  for (int t = 0; t < NT; ++t) {
    // tile-boundary sync: own staging of buf(t) complete, then barrier
    asm volatile("s_waitcnt vmcnt(0)" ::: "memory");
    BAR();

    const u16* A = &lds[t & 1][0][0];
    const u16* B = &lds[t & 1][1][0];

    // ---- ALL 16 ds_read_b128, consumption order ----
#pragma unroll
    for (int n = 0; n < 4; ++n)
#pragma unroll
      for (int s = 0; s < 2; ++s)
        bf[n][s] = *reinterpret_cast<const bf16x8*>(
            B + (brow + n * 16) * 64 + (fksw ^ (s << 5)));
#pragma unroll
    for (int m = 0; m < 4; ++m)
#pragma unroll
      for (int s = 0; s < 2; ++s)
        af[m][s] = *reinterpret_cast<const bf16x8*>(
            A + (arow + m * 16) * 64 + (fksw ^ (s << 5)));

    // staging for t+1 (unconditional, clamped)
    STAGE(t + 1, 0); STAGE(t + 1, 1);

    // ---- 32 MFMA ----
    __builtin_amdgcn_s_setprio(1);
#pragma unroll
    for (int m = 0; m < 4; ++m)
#pragma unroll
      for (int n = 0; n < 4; ++n)
#pragma unroll
        for (int s = 0; s < 2; ++s)
          acc[m][n] = __builtin_amdgcn_mfma_f32_16x16x32_bf16(
              af[m][s], bf[n][s], acc[m][n], 0, 0, 0);
    __builtin_amdgcn_s_setprio(0);
  }

  // epilogue: C/D layout col = l&15, row = 4*(l>>4)+j
  const int orow = tm * 128 + wr * 64 + ((l >> 4) << 2);
  const int ocol = tn * 128 + wc * 64 + (l & 15);
#pragma unroll
  for (int m = 0; m < 4; ++m)
#pragma unroll
    for (int n = 0; n < 4; ++n) {
      float* cp = C + (size_t)(orow + m * 16) * GN + (ocol + n * 16);
#pragma unroll
      for (int j = 0; j < 4; ++j) cp[(size_t)j * GN] = acc[m][n][j];
    }
}

extern "C" void kernel_launch(void* const* d_in, const int* in_sizes, int n_in,
                              void* d_out, int out_size, void* d_ws, size_t ws_size,
                              hipStream_t stream) {
  const float* x  = (const float*)d_in[0];
  const float* W  = (const float*)d_in[1];
  const float* lA = (const float*)d_in[2];
  const float* lB = (const float*)d_in[3];
  float* out = (float*)d_out;

  u16* weff = (u16*)d_ws;                                        // 32 MiB
  u16* xb = (u16*)((char*)d_ws + (size_t)GN * GK * sizeof(u16)); // 64 MiB

  prep<<<GN + (GM * GK) / (256 * 16), 256, 0, stream>>>(W, lA, lB, weff, x, xb);
  gemm128<<<(GM / 128) * (GN / 128), 256, 0, stream>>>(xb, weff, out);
}

// Round 17
// 292.466 us; speedup vs baseline: 1.1642x; 1.1642x over previous
//
#include <hip/hip_runtime.h>
#include <hip/hip_bf16.h>

typedef unsigned short u16;
typedef __attribute__((ext_vector_type(8))) __bf16 bf16x8;
typedef __attribute__((ext_vector_type(4))) float f32x4;
typedef __attribute__((ext_vector_type(8))) unsigned short ushort8;

#define GM 8192
#define GN 4096
#define GK 4096
#define NT (GK / 64)  // 64 K-tiles of BK=64

__device__ __forceinline__ u16 f2bf(float f) {
  unsigned u = __float_as_uint(f);
  u += 0x7fffu + ((u >> 16) & 1u);
  return (u16)(u >> 16);
}

// ---- kernel 1: fused pre-pass (R15, kept — measured ~50us, ~92% of the
// 288MB-traffic HBM roofline).
// blocks [0, GN):        Weff[o][:] = bf16(W[o][:] + 2 * (B@A)[o][:])
// blocks [GN, GN+2048):  xb = bf16(x), 16 elems/thread
__global__ void prep(const float* __restrict__ W,
                     const float* __restrict__ lA,
                     const float* __restrict__ lB,
                     u16* __restrict__ Weff,
                     const float* __restrict__ x,
                     u16* __restrict__ xb) {
  const int bid = blockIdx.x;
  if (bid < GN) {
    const int o = bid;
    float b[8];
#pragma unroll
    for (int r = 0; r < 8; ++r) b[r] = 2.0f * lB[o * 8 + r];
    const float* wrow = W + (size_t)o * GK;
    u16* orow = Weff + (size_t)o * GK;
    for (int d = threadIdx.x * 4; d < GK; d += blockDim.x * 4) {
      float4 w = *reinterpret_cast<const float4*>(wrow + d);
      float a0 = w.x, a1 = w.y, a2 = w.z, a3 = w.w;
#pragma unroll
      for (int r = 0; r < 8; ++r) {
        float4 a = *reinterpret_cast<const float4*>(lA + r * GK + d);
        a0 += b[r] * a.x; a1 += b[r] * a.y; a2 += b[r] * a.z; a3 += b[r] * a.w;
      }
      ushort4 p;
      p.x = f2bf(a0); p.y = f2bf(a1); p.z = f2bf(a2); p.w = f2bf(a3);
      *reinterpret_cast<ushort4*>(orow + d) = p;
    }
  } else {
    const size_t base = ((size_t)(bid - GN) * 256 + threadIdx.x) * 16;
#pragma unroll
    for (int h = 0; h < 2; ++h) {
      const size_t i = base + h * 8;
      float4 v0 = *reinterpret_cast<const float4*>(x + i);
      float4 v1 = *reinterpret_cast<const float4*>(x + i + 4);
      ushort8 o;
      o[0] = f2bf(v0.x); o[1] = f2bf(v0.y); o[2] = f2bf(v0.z); o[3] = f2bf(v0.w);
      o[4] = f2bf(v1.x); o[5] = f2bf(v1.y); o[6] = f2bf(v1.z); o[7] = f2bf(v1.w);
      *reinterpret_cast<ushort8*>(xb + i) = o;
    }
  }
}

// ---- kernel 2: 256x256-tile free-flow GEMM (R11/R15 measured-best family:
// 230-233us, MfmaUtil 54.6%, 0 bank conflicts).
// Changes this round: (a) dropped the T19 SGB script (3x measured null);
// (b) C epilogue uses __builtin_nontemporal_store — C is 128MB write-once,
// streaming it past L2 avoids evicting A/B panels (gemm FETCH ~300MB vs
// 96MB unique suggests eviction-driven re-fetch).
// Design-space record (7 variants): phase-locked 8-phase (R3-R5, 257-265us),
// free-flow 1-barrier (R6/R7/R11, 233-240), one-phase-lag (R9, 231),
// 32x32 MFMA (R10, 307), SGB-pinned (R11, 230), 128^2 2-blk/CU (R16, 297),
// fused-cvt (R12-14, 332-640). Plateau: ~4330 cyc/K-tile; MFMA floor 2483.
// 1-block/CU is forced by the 128-reg accumulator (256-reg/wave budget).
__device__ __forceinline__ void gload16(const u16* g, u16* l) {
  __builtin_amdgcn_global_load_lds(
      (const __attribute__((address_space(1))) void*)g,
      (__attribute__((address_space(3))) void*)l, 16, 0, 0);
}

#define BAR()                                  \
  do {                                         \
    asm volatile("" ::: "memory");             \
    __builtin_amdgcn_s_barrier();              \
    asm volatile("" ::: "memory");             \
  } while (0)

__global__ __launch_bounds__(512, 2) void gemm256(const u16* __restrict__ Ab,
                                                  const u16* __restrict__ Bb,
                                                  float* __restrict__ C) {
  // [buf][0=A,1=B][row*64 + k], 2*2*16384*2B = 128 KiB
  __shared__ u16 lds[2][2][256 * 64];

  const int tid = threadIdx.x;
  const int wv = tid >> 6;
  const int l = tid & 63;

  // XCD-aware swizzle: 512 blocks, 512 % 8 == 0 -> simple bijective form
  const int nwg = gridDim.x;
  const int cpx = nwg >> 3;
  const int wg = ((int)blockIdx.x & 7) * cpx + ((int)blockIdx.x >> 3);
  const int tm = wg >> 4;   // GN/256 = 16 tiles in N
  const int tn = wg & 15;

  const int wr = wv >> 2;   // 0..1  (M split)
  const int wc = wv & 3;    // 0..3  (N split)

  // --- staging constants ---
  const int srow = (wv << 3) + (l >> 3);
  const int srl = ((wv & 1) << 3) | (l >> 3);          // row bits 0..3
  const int skel = ((l & 7) << 3) ^ ((srl & 0xE) << 2);
  const u16* aG = Ab + (size_t)(tm * 256) * GK;
  const u16* bG = Bb + (size_t)(tn * 256) * GK;

  // --- reader constants ---
  const int frow = l & 15;
  const int fksw = ((l >> 4) << 3) ^ ((frow & 0xE) << 2);
  const int arow = wr * 128 + frow;
  const int brow = wc * 64 + frow;

  // stage half-tile: th = K-tile (clamped), r: 0=A0,1=A1,2=B0,3=B1
  auto STAGE = [&](int th, int r) {
    const int tc = th < NT ? th : NT - 1;  // clamp (tail garbage never read)
    const int k0 = tc << 6;
    const u16* src = (r < 2 ? aG : bG) +
                     (size_t)((r & 1) * 128 + srow) * GK + k0 + skel;
    u16* dst = &lds[th & 1][r >> 1][(r & 1) * 8192 + wv * 512];
#pragma unroll
    for (int j = 0; j < 2; ++j)
      gload16(src + (size_t)(j * 64) * GK, dst + j * 4096);
  };

  // prologue: stage tile 0 only (1-deep pipeline)
  STAGE(0, 0); STAGE(0, 1); STAGE(0, 2); STAGE(0, 3);

  f32x4 acc[8][4] = {};
  bf16x8 af_lo[4][2], af_hi[4][2], bfr0[2][2], bfr1[2][2];

  for (int t = 0; t < NT; ++t) {
    // tile-boundary sync: own staging of buf(t) complete (vmcnt), then
    // barrier = everyone done staging t AND done reading t-1.
    asm volatile("s_waitcnt vmcnt(0)" ::: "memory");
    BAR();

    const u16* A = &lds[t & 1][0][0];
    const u16* B = &lds[t & 1][1][0];

    // ---- ALL 24 ds_read_b128, consumption order ----
#pragma unroll
    for (int n = 0; n < 2; ++n)
#pragma unroll
      for (int s = 0; s < 2; ++s)
        bfr0[n][s] = *reinterpret_cast<const bf16x8*>(
            B + (brow + n * 16) * 64 + (fksw ^ (s << 5)));
#pragma unroll
    for (int m = 0; m < 4; ++m)
#pragma unroll
      for (int s = 0; s < 2; ++s)
        af_lo[m][s] = *reinterpret_cast<const bf16x8*>(
            A + (arow + m * 16) * 64 + (fksw ^ (s << 5)));
#pragma unroll
    for (int n = 0; n < 2; ++n)
#pragma unroll
      for (int s = 0; s < 2; ++s)
        bfr1[n][s] = *reinterpret_cast<const bf16x8*>(
            B + (brow + (n + 2) * 16) * 64 + (fksw ^ (s << 5)));
#pragma unroll
    for (int m = 0; m < 4; ++m)
#pragma unroll
      for (int s = 0; s < 2; ++s)
        af_hi[m][s] = *reinterpret_cast<const bf16x8*>(
            A + (arow + (m + 4) * 16) * 64 + (fksw ^ (s << 5)));

    // staging for t+1 (unconditional, clamped)
    STAGE(t + 1, 0); STAGE(t + 1, 1); STAGE(t + 1, 2); STAGE(t + 1, 3);

    // ---- 64 MFMA in quadrant order ----
    __builtin_amdgcn_s_setprio(1);
#pragma unroll
    for (int m = 0; m < 4; ++m)
#pragma unroll
      for (int n = 0; n < 2; ++n)
#pragma unroll
        for (int s = 0; s < 2; ++s)
          acc[m][n] = __builtin_amdgcn_mfma_f32_16x16x32_bf16(
              af_lo[m][s], bfr0[n][s], acc[m][n], 0, 0, 0);
#pragma unroll
    for (int m = 0; m < 4; ++m)
#pragma unroll
      for (int n = 0; n < 2; ++n)
#pragma unroll
        for (int s = 0; s < 2; ++s)
          acc[m][n + 2] = __builtin_amdgcn_mfma_f32_16x16x32_bf16(
              af_lo[m][s], bfr1[n][s], acc[m][n + 2], 0, 0, 0);
#pragma unroll
    for (int m = 0; m < 4; ++m)
#pragma unroll
      for (int n = 0; n < 2; ++n)
#pragma unroll
        for (int s = 0; s < 2; ++s)
          acc[m + 4][n + 2] = __builtin_amdgcn_mfma_f32_16x16x32_bf16(
              af_hi[m][s], bfr1[n][s], acc[m + 4][n + 2], 0, 0, 0);
#pragma unroll
    for (int m = 0; m < 4; ++m)
#pragma unroll
      for (int n = 0; n < 2; ++n)
#pragma unroll
        for (int s = 0; s < 2; ++s)
          acc[m + 4][n] = __builtin_amdgcn_mfma_f32_16x16x32_bf16(
              af_hi[m][s], bfr0[n][s], acc[m + 4][n], 0, 0, 0);
    __builtin_amdgcn_s_setprio(0);
  }

  // epilogue: C/D layout col = l&15, row = 4*(l>>4)+j.
  // Nontemporal: C is write-once, keep it out of L2.
  const int orow = tm * 256 + wr * 128 + ((l >> 4) << 2);
  const int ocol = tn * 256 + wc * 64 + (l & 15);
#pragma unroll
  for (int m = 0; m < 8; ++m)
#pragma unroll
    for (int n = 0; n < 4; ++n) {
      float* cp = C + (size_t)(orow + m * 16) * GN + (ocol + n * 16);
#pragma unroll
      for (int j = 0; j < 4; ++j)
        __builtin_nontemporal_store(acc[m][n][j], cp + (size_t)j * GN);
    }
}

extern "C" void kernel_launch(void* const* d_in, const int* in_sizes, int n_in,
                              void* d_out, int out_size, void* d_ws, size_t ws_size,
                              hipStream_t stream) {
  const float* x  = (const float*)d_in[0];
  const float* W  = (const float*)d_in[1];
  const float* lA = (const float*)d_in[2];
  const float* lB = (const float*)d_in[3];
  float* out = (float*)d_out;

  u16* weff = (u16*)d_ws;                                        // 32 MiB
  u16* xb = (u16*)((char*)d_ws + (size_t)GN * GK * sizeof(u16)); // 64 MiB

  prep<<<GN + (GM * GK) / (256 * 16), 256, 0, stream>>>(W, lA, lB, weff, x, xb);
  gemm256<<<(GM / 256) * (GN / 256), 512, 0, stream>>>(xb, weff, out);
}

// Round 18
// 287.240 us; speedup vs baseline: 1.1854x; 1.0182x over previous
//
#include <hip/hip_runtime.h>
#include <hip/hip_bf16.h>

typedef unsigned short u16;
typedef __attribute__((ext_vector_type(8))) __bf16 bf16x8;
typedef __attribute__((ext_vector_type(4))) float f32x4;
typedef __attribute__((ext_vector_type(8))) unsigned short ushort8;

#define GM 8192
#define GN 4096
#define GK 4096
#define NT (GK / 64)  // 64 K-tiles of BK=64

__device__ __forceinline__ u16 f2bf(float f) {
  unsigned u = __float_as_uint(f);
  u += 0x7fffu + ((u >> 16) & 1u);
  return (u16)(u >> 16);
}

// ---- kernel 1: fused pre-pass (measured ~50us, ~92% of the 288MB-traffic
// HBM roofline).
// blocks [0, GN):        Weff[o][:] = bf16(W[o][:] + 2 * (B@A)[o][:])
// blocks [GN, GN+2048):  xb = bf16(x), 16 elems/thread
__global__ void prep(const float* __restrict__ W,
                     const float* __restrict__ lA,
                     const float* __restrict__ lB,
                     u16* __restrict__ Weff,
                     const float* __restrict__ x,
                     u16* __restrict__ xb) {
  const int bid = blockIdx.x;
  if (bid < GN) {
    const int o = bid;
    float b[8];
#pragma unroll
    for (int r = 0; r < 8; ++r) b[r] = 2.0f * lB[o * 8 + r];
    const float* wrow = W + (size_t)o * GK;
    u16* orow = Weff + (size_t)o * GK;
    for (int d = threadIdx.x * 4; d < GK; d += blockDim.x * 4) {
      float4 w = *reinterpret_cast<const float4*>(wrow + d);
      float a0 = w.x, a1 = w.y, a2 = w.z, a3 = w.w;
#pragma unroll
      for (int r = 0; r < 8; ++r) {
        float4 a = *reinterpret_cast<const float4*>(lA + r * GK + d);
        a0 += b[r] * a.x; a1 += b[r] * a.y; a2 += b[r] * a.z; a3 += b[r] * a.w;
      }
      ushort4 p;
      p.x = f2bf(a0); p.y = f2bf(a1); p.z = f2bf(a2); p.w = f2bf(a3);
      *reinterpret_cast<ushort4*>(orow + d) = p;
    }
  } else {
    const size_t base = ((size_t)(bid - GN) * 256 + threadIdx.x) * 16;
#pragma unroll
    for (int h = 0; h < 2; ++h) {
      const size_t i = base + h * 8;
      float4 v0 = *reinterpret_cast<const float4*>(x + i);
      float4 v1 = *reinterpret_cast<const float4*>(x + i + 4);
      ushort8 o;
      o[0] = f2bf(v0.x); o[1] = f2bf(v0.y); o[2] = f2bf(v0.z); o[3] = f2bf(v0.w);
      o[4] = f2bf(v1.x); o[5] = f2bf(v1.y); o[6] = f2bf(v1.z); o[7] = f2bf(v1.w);
      *reinterpret_cast<ushort8*>(xb + i) = o;
    }
  }
}

// ---- kernel 2: 256x256-tile free-flow GEMM — FINAL (R15 exact, measured
// best: gemm 231-233us / 1195 TF / MfmaUtil 54.6% / 0 bank conflicts).
// Structure: 8 waves (2Mx4N), BK=64, 128KiB LDS double-buffer, 1-deep
// global_load_lds staging (pre-swizzled source), ONE vmcnt(0)+s_barrier
// per K-tile, all 24 ds_read_b128 issued up front in consumption order,
// 64 MFMA quadrant stream with setprio, 3-bit LDS XOR swizzle, bijective
// XCD blockIdx swizzle, plain coalesced C stores (NT-store regressed:
// +43MB HBM writes from partial-line bypass).
// Plateau record (10 variants, R3-R17): all legal schedules converge at
// ~4330 cyc/K-tile. Constraint: MFMA floor 2483 cyc/tile; LDS pipe ~2800
// cyc/tile (same-pipe reads+DMA); 128-reg acc forces 1 block/CU, so the
// per-tile barrier re-syncs all 8 waves and the read-hump has no
// co-resident block to hide under. ~45% idle is the cost of that sync.
__device__ __forceinline__ void gload16(const u16* g, u16* l) {
  __builtin_amdgcn_global_load_lds(
      (const __attribute__((address_space(1))) void*)g,
      (__attribute__((address_space(3))) void*)l, 16, 0, 0);
}

#define BAR()                                  \
  do {                                         \
    asm volatile("" ::: "memory");             \
    __builtin_amdgcn_s_barrier();              \
    asm volatile("" ::: "memory");             \
  } while (0)

__global__ __launch_bounds__(512, 2) void gemm256(const u16* __restrict__ Ab,
                                                  const u16* __restrict__ Bb,
                                                  float* __restrict__ C) {
  // [buf][0=A,1=B][row*64 + k], 2*2*16384*2B = 128 KiB
  __shared__ u16 lds[2][2][256 * 64];

  const int tid = threadIdx.x;
  const int wv = tid >> 6;
  const int l = tid & 63;

  // XCD-aware swizzle: 512 blocks, 512 % 8 == 0 -> simple bijective form
  const int nwg = gridDim.x;
  const int cpx = nwg >> 3;
  const int wg = ((int)blockIdx.x & 7) * cpx + ((int)blockIdx.x >> 3);
  const int tm = wg >> 4;   // GN/256 = 16 tiles in N
  const int tn = wg & 15;

  const int wr = wv >> 2;   // 0..1  (M split)
  const int wc = wv & 3;    // 0..3  (N split)

  // --- staging constants ---
  const int srow = (wv << 3) + (l >> 3);
  const int srl = ((wv & 1) << 3) | (l >> 3);          // row bits 0..3
  const int skel = ((l & 7) << 3) ^ ((srl & 0xE) << 2);
  const u16* aG = Ab + (size_t)(tm * 256) * GK;
  const u16* bG = Bb + (size_t)(tn * 256) * GK;

  // --- reader constants ---
  const int frow = l & 15;
  const int fksw = ((l >> 4) << 3) ^ ((frow & 0xE) << 2);
  const int arow = wr * 128 + frow;
  const int brow = wc * 64 + frow;

  // stage half-tile: th = K-tile (clamped), r: 0=A0,1=A1,2=B0,3=B1
  auto STAGE = [&](int th, int r) {
    const int tc = th < NT ? th : NT - 1;  // clamp (tail garbage never read)
    const int k0 = tc << 6;
    const u16* src = (r < 2 ? aG : bG) +
                     (size_t)((r & 1) * 128 + srow) * GK + k0 + skel;
    u16* dst = &lds[th & 1][r >> 1][(r & 1) * 8192 + wv * 512];
#pragma unroll
    for (int j = 0; j < 2; ++j)
      gload16(src + (size_t)(j * 64) * GK, dst + j * 4096);
  };

  // prologue: stage tile 0 only (1-deep pipeline)
  STAGE(0, 0); STAGE(0, 1); STAGE(0, 2); STAGE(0, 3);

  f32x4 acc[8][4] = {};
  bf16x8 af_lo[4][2], af_hi[4][2], bfr0[2][2], bfr1[2][2];

  for (int t = 0; t < NT; ++t) {
    // tile-boundary sync: own staging of buf(t) complete (vmcnt), then
    // barrier = everyone done staging t AND done reading t-1.
    asm volatile("s_waitcnt vmcnt(0)" ::: "memory");
    BAR();

    const u16* A = &lds[t & 1][0][0];
    const u16* B = &lds[t & 1][1][0];

    // ---- ALL 24 ds_read_b128, consumption order ----
#pragma unroll
    for (int n = 0; n < 2; ++n)
#pragma unroll
      for (int s = 0; s < 2; ++s)
        bfr0[n][s] = *reinterpret_cast<const bf16x8*>(
            B + (brow + n * 16) * 64 + (fksw ^ (s << 5)));
#pragma unroll
    for (int m = 0; m < 4; ++m)
#pragma unroll
      for (int s = 0; s < 2; ++s)
        af_lo[m][s] = *reinterpret_cast<const bf16x8*>(
            A + (arow + m * 16) * 64 + (fksw ^ (s << 5)));
#pragma unroll
    for (int n = 0; n < 2; ++n)
#pragma unroll
      for (int s = 0; s < 2; ++s)
        bfr1[n][s] = *reinterpret_cast<const bf16x8*>(
            B + (brow + (n + 2) * 16) * 64 + (fksw ^ (s << 5)));
#pragma unroll
    for (int m = 0; m < 4; ++m)
#pragma unroll
      for (int s = 0; s < 2; ++s)
        af_hi[m][s] = *reinterpret_cast<const bf16x8*>(
            A + (arow + (m + 4) * 16) * 64 + (fksw ^ (s << 5)));

    // staging for t+1 (unconditional, clamped)
    STAGE(t + 1, 0); STAGE(t + 1, 1); STAGE(t + 1, 2); STAGE(t + 1, 3);

    // ---- 64 MFMA in quadrant order ----
    __builtin_amdgcn_s_setprio(1);
#pragma unroll
    for (int m = 0; m < 4; ++m)
#pragma unroll
      for (int n = 0; n < 2; ++n)
#pragma unroll
        for (int s = 0; s < 2; ++s)
          acc[m][n] = __builtin_amdgcn_mfma_f32_16x16x32_bf16(
              af_lo[m][s], bfr0[n][s], acc[m][n], 0, 0, 0);
#pragma unroll
    for (int m = 0; m < 4; ++m)
#pragma unroll
      for (int n = 0; n < 2; ++n)
#pragma unroll
        for (int s = 0; s < 2; ++s)
          acc[m][n + 2] = __builtin_amdgcn_mfma_f32_16x16x32_bf16(
              af_lo[m][s], bfr1[n][s], acc[m][n + 2], 0, 0, 0);
#pragma unroll
    for (int m = 0; m < 4; ++m)
#pragma unroll
      for (int n = 0; n < 2; ++n)
#pragma unroll
        for (int s = 0; s < 2; ++s)
          acc[m + 4][n + 2] = __builtin_amdgcn_mfma_f32_16x16x32_bf16(
              af_hi[m][s], bfr1[n][s], acc[m + 4][n + 2], 0, 0, 0);
#pragma unroll
    for (int m = 0; m < 4; ++m)
#pragma unroll
      for (int n = 0; n < 2; ++n)
#pragma unroll
        for (int s = 0; s < 2; ++s)
          acc[m + 4][n] = __builtin_amdgcn_mfma_f32_16x16x32_bf16(
              af_hi[m][s], bfr0[n][s], acc[m + 4][n], 0, 0, 0);
    __builtin_amdgcn_s_setprio(0);
  }

  // epilogue: C/D layout col = l&15, row = 4*(l>>4)+j (plain stores)
  const int orow = tm * 256 + wr * 128 + ((l >> 4) << 2);
  const int ocol = tn * 256 + wc * 64 + (l & 15);
#pragma unroll
  for (int m = 0; m < 8; ++m)
#pragma unroll
    for (int n = 0; n < 4; ++n) {
      float* cp = C + (size_t)(orow + m * 16) * GN + (ocol + n * 16);
#pragma unroll
      for (int j = 0; j < 4; ++j) cp[(size_t)j * GN] = acc[m][n][j];
    }
}

extern "C" void kernel_launch(void* const* d_in, const int* in_sizes, int n_in,
                              void* d_out, int out_size, void* d_ws, size_t ws_size,
                              hipStream_t stream) {
  const float* x  = (const float*)d_in[0];
  const float* W  = (const float*)d_in[1];
  const float* lA = (const float*)d_in[2];
  const float* lB = (const float*)d_in[3];
  float* out = (float*)d_out;

  u16* weff = (u16*)d_ws;                                        // 32 MiB
  u16* xb = (u16*)((char*)d_ws + (size_t)GN * GK * sizeof(u16)); // 64 MiB

  prep<<<GN + (GM * GK) / (256 * 16), 256, 0, stream>>>(W, lA, lB, weff, x, xb);
  gemm256<<<(GM / 256) * (GN / 256), 512, 0, stream>>>(xb, weff, out);
}